// Round 1
// baseline (4270.093 us; speedup 1.0000x reference)
//
#include <hip/hip_runtime.h>
#include <stdint.h>

// 2-layer masked GRU encoder, B=64 T=512 D=U=512. f32 in/out, mask=int32.
// 256 WGs lockstep, software-pipelined: even WGs (pipe A) = layer 0 at phase s,
// odd WGs (pipe B) = layer 1 at phase s-1. One flag-barrier per phase.
// All cross-WG data via RELAXED agent-scope atomics (sc1, MALL-coherent).
// This revision: latency-trimmed phase --
//   * h operands loaded global->MFMA-fragment directly (no LDS staging hop)
//   * u16-packed flags: 1 ld8/lane/poll + s_sleep backoff
//   * publish packed in-register via shfl (no pub16 LDS), 3 syncs/phase
//   * out[]/final-h stores after flag => vmcnt(0) waits only the publishes
//   * st0 XOR-swizzle + lane-contiguous accs => bank-conflict-free LDS
// ws: h0pub[2][64][512]bf16 | h1pub[2][64][512]bf16 | h0n[2][64][512]bf16
//     | flags[513][256]u16   == 655,872 bytes.

#define TT 512

typedef __attribute__((ext_vector_type(8))) short bfrag_t;   // 8 x bf16
typedef __attribute__((ext_vector_type(4))) float f32x4;

__device__ inline unsigned short f2bf(float f) {
  unsigned u = __float_as_uint(f);
  unsigned r = u + 0x7FFFu + ((u >> 16) & 1u);   // RNE
  return (unsigned short)(r >> 16);
}
__device__ inline unsigned pack2(float lo, float hi) {
  return (unsigned)f2bf(lo) | ((unsigned)f2bf(hi) << 16);
}
__device__ inline float sigmoidf_(float x) { return 1.0f / (1.0f + __expf(-x)); }
__device__ inline float fast_tanh(float x) {
  float ax = fabsf(x);
  float e = __expf(-2.0f * ax);
  float t = (1.0f - e) / (1.0f + e);
  return x < 0.0f ? -t : t;
}

__device__ inline void st8(void* p, unsigned long long v) {
  __hip_atomic_store((unsigned long long*)p, v, __ATOMIC_RELAXED, __HIP_MEMORY_SCOPE_AGENT);
}
__device__ inline unsigned long long ld8(const void* p) {
  return __hip_atomic_load((const unsigned long long*)p, __ATOMIC_RELAXED, __HIP_MEMORY_SCOPE_AGENT);
}
// 8 bf16 fragment loaded straight from MALL-coherent global (two relaxed 8B loads)
__device__ inline bfrag_t ldfrag(const unsigned short* p) {
  union { unsigned long long q[2]; bfrag_t v; } u;
  u.q[0] = ld8(p);
  u.q[1] = ld8(p + 4);
  return u.v;
}

// All 256 u16 flags for one step fit in 64 lanes x 8B: ONE load per lane per poll.
__device__ inline void spinflags(const unsigned short* f, int s_expect) {
  const int lane = threadIdx.x & 63;
  const unsigned long long* p = (const unsigned long long*)f + lane;
  const unsigned long long rep = 0x0001000100010001ull * (unsigned long long)s_expect;
  for (;;) {
    unsigned long long v = __hip_atomic_load(p, __ATOMIC_RELAXED, __HIP_MEMORY_SCOPE_AGENT);
    if (__ballot(v == rep) == 0xFFFFFFFFFFFFFFFFull) break;
    __builtin_amdgcn_s_sleep(1);   // ~64cy backoff: cuts flag-line contention
  }
}

extern "C" __global__ void __launch_bounds__(256, 1)
gru2_lockstep(const float* __restrict__ x,     // [64][512][512] f32
              const int*   __restrict__ mask,  // [64][512] i32
              const float* __restrict__ W0,    // [512][1536] f32
              const float* __restrict__ U0,
              const float* __restrict__ b0,    // [2][1536]
              const float* __restrict__ W1,
              const float* __restrict__ U1,
              const float* __restrict__ b1,
              float* __restrict__ out,         // [16777216 + 2*32768] f32
              unsigned char* __restrict__ ws)
{
  extern __shared__ unsigned short sm[];
  unsigned short* wt  = sm;                 // [96][520] bf16 transposed weights
  unsigned short* st0 = sm + 96 * 520;      // [16][512] x operand, XOR-swizzled chunks
  float* accs = (float*)(st0 + 16 * 512);   // [4][256] lane-contiguous

  unsigned short* h0pub = (unsigned short*)ws;             // [2][64][512] bf16 (masked h0)
  unsigned short* h1pub = (unsigned short*)(ws + 131072);  // [2][64][512] bf16 (masked h1)
  unsigned short* h0n   = (unsigned short*)(ws + 262144);  // [2][64][512] bf16 (UNMASKED h0n)
  unsigned short* flags = (unsigned short*)(ws + 393216);  // [513][256] u16

  const int tid  = threadIdx.x;
  const int wg   = blockIdx.x;
  const int pipe = wg & 1;
  const int idx  = wg >> 1;
  const int mi = idx & 3,  ni = idx >> 2;
  const int r0 = mi * 16,  c0 = ni * 16;
  const int wave = tid >> 6, lane = tid & 63;
  const int quad = lane >> 4, n16 = lane & 15;

  const float* Wm = pipe ? W1 : W0;
  const float* Um = pipe ? U1 : U0;
  const float* bp = pipe ? b1 : b0;
  unsigned short* hpub = pipe ? h1pub : h0pub;

  // ---- one-time: transpose my 48 gate-cols of W and U into LDS bf16 [n][k] ----
  {
    const int col  = tid & 15;
    const int ksub = tid >> 4;
    for (int k0 = 0; k0 < 512; k0 += 16) {
      const int k = k0 + ksub;
      const float* M0 = Wm + (size_t)k * 1536;
      const float* M1 = Um + (size_t)k * 1536;
      #pragma unroll
      for (int g = 0; g < 3; ++g) {
        wt[(g * 16 + col) * 520 + k]      = f2bf(M0[g * 512 + c0 + col]);
        wt[(48 + g * 16 + col) * 520 + k] = f2bf(M1[g * 512 + c0 + col]);
      }
    }
  }
  __syncthreads();

  // wave roles: w0=z (concat x|h), w1=r (concat), w2=ih (x), w3=hh (h)
  const int g  = (wave < 2) ? wave : 2;
  const int np = (wave < 2) ? 2 : 1;

  bfrag_t bw0[16], bw1[16];
  {
    const int mat0 = (wave == 3) ? 1 : 0;
    const int row0 = mat0 * 48 + g * 16 + n16;
    #pragma unroll
    for (int f = 0; f < 16; ++f)
      bw0[f] = *(const bfrag_t*)&wt[row0 * 520 + f * 32 + quad * 8];
    if (np == 2) {
      const int row1 = 48 + g * 16 + n16;
      #pragma unroll
      for (int f = 0; f < 16; ++f)
        bw1[f] = *(const bfrag_t*)&wt[row1 * 520 + f * 32 + quad * 8];
    }
  }

  float bsc;
  {
    const int colg = g * 512 + c0 + n16;
    const float bi = bp[colg];
    const float bh = bp[1536 + colg];
    bsc = (wave < 2) ? (bi + bh) : ((wave == 2) ? bi : bh);
  }

  float hcar = 0.0f;   // fp32 carry of my h element (WG-local!)
  float oprev = 0.0f;
  const int erow = tid >> 4, ecol = tid & 15;
  const int eb = r0 + erow, ec = c0 + ecol;

  for (int s = 0; s <= TT; ++s) {
    const bool actA = (pipe == 0) && (s < TT);
    const bool actB = (pipe == 1) && (s > 0);
    const bool act  = actA || actB;
    const int  t    = pipe ? (s - 1) : s;

    // mask prefetch (regular cached load, overlapped with everything below)
    const int mv = act ? mask[(size_t)eb * 512 + t] : 0;

    // ---- barrier wait (wave 0) overlapped with pipe-A x(s) prestage ----
    if (actA && tid >= 128) {
      const int sm2 = (tid - 128) >> 3;     // 0..15 row
      const int k8  = tid & 7;              // 0..7 chunk sub-index
      const float* src = x + (((size_t)(r0 + sm2) * 512 + s) * 512 + k8 * 8);
      uint4* dstrow = (uint4*)(st0 + sm2 * 512);
      #pragma unroll
      for (int c = 0; c < 8; ++c) {
        float4 a = *(const float4*)(src + c * 64);
        float4 b = *(const float4*)(src + c * 64 + 4);
        uint4 u;
        u.x = pack2(a.x, a.y);  u.y = pack2(a.z, a.w);
        u.z = pack2(b.x, b.y);  u.w = pack2(b.z, b.w);
        dstrow[(k8 + 8 * c) ^ (sm2 & 7)] = u;   // XOR-swizzled chunk: conflict-free
      }
    } else if (wave == 0 && s > 0) {
      spinflags(flags + (size_t)(s - 1) * 256, s);
    }
    __syncthreads();   // S1: flags confirmed + st0 ready

    // ---- MFMA: h operands loaded DIRECTLY from MALL-coherent global ----
    if (act) {
      f32x4 acc = {bsc, bsc, bsc, bsc};
      const size_t rowoff = (size_t)(r0 + n16) * 512 + quad * 8;
      const unsigned short* hsP = hpub + (size_t)((t + 1) & 1) * 32768 + rowoff;  // self-pipe h(t)
      if (pipe == 0 && wave != 3) {
        // x operand from LDS (swizzled)
        const int rbase = n16 * 512;
        const int sw = n16 & 7;
        #pragma unroll
        for (int f = 0; f < 16; ++f) {
          bfrag_t a = *(const bfrag_t*)&st0[rbase + (((quad + 4 * f) ^ sw) << 3)];
          acc = __builtin_amdgcn_mfma_f32_16x16x32_bf16(a, bw0[f], acc, 0, 0, 0);
        }
      } else {
        // wave3: self-pipe h; pipe-B waves 0..2: h0n (layer-0 output, unmasked)
        const unsigned short* g0 = (wave == 3) ? hsP
                                 : h0n + (size_t)(t & 1) * 32768 + rowoff;
        bfrag_t af[16];
        #pragma unroll
        for (int f = 0; f < 16; ++f) af[f] = ldfrag(g0 + f * 32);
        #pragma unroll
        for (int f = 0; f < 16; ++f)
          acc = __builtin_amdgcn_mfma_f32_16x16x32_bf16(af[f], bw0[f], acc, 0, 0, 0);
      }
      if (np == 2) {
        bfrag_t ah[16];
        #pragma unroll
        for (int f = 0; f < 16; ++f) ah[f] = ldfrag(hsP + f * 32);
        #pragma unroll
        for (int f = 0; f < 16; ++f)
          acc = __builtin_amdgcn_mfma_f32_16x16x32_bf16(ah[f], bw1[f], acc, 0, 0, 0);
      }
      // lane-contiguous b128 store: conflict-free
      *(f32x4*)&accs[wave * 256 + lane * 4] = acc;
    }
    __syncthreads();   // S2: accs ready (also fences st0 reads)

    // ---- elementwise GRU cell + in-register publish pack ----
    if (act) {
      const int aidx = ((erow >> 2) * 16 + ecol) * 4 + (erow & 3);
      const float zv = sigmoidf_(accs[aidx]);
      const float rv = sigmoidf_(accs[256 + aidx]);
      const float candv = fast_tanh(accs[512 + aidx] + rv * accs[768 + aidx]);
      const float hold = hcar;
      const float hn = zv * hold + (1.0f - zv) * candv;
      const bool  m  = mv != 0;
      const float hc = m ? hn : hold;
      hcar = hc;
      if (pipe == 1) oprev = m ? hn : oprev;

      // pack 4 neighboring columns (lanes l..l+3, never crossing a 16-lane row)
      const float hc1 = __shfl_down(hc, 1);
      const float hc2 = __shfl_down(hc, 2);
      const float hc3 = __shfl_down(hc, 3);
      if (pipe == 0) {
        const float hn1 = __shfl_down(hn, 1);
        const float hn2 = __shfl_down(hn, 2);
        const float hn3 = __shfl_down(hn, 3);
        if ((tid & 3) == 0) {
          const size_t off = (size_t)(t & 1) * 32768 + (size_t)eb * 512 + ec;
          st8(h0pub + off, (unsigned long long)pack2(hc, hc1) |
                           ((unsigned long long)pack2(hc2, hc3) << 32));
          st8(h0n + off,   (unsigned long long)pack2(hn, hn1) |
                           ((unsigned long long)pack2(hn2, hn3) << 32));
        }
      } else {
        if ((tid & 3) == 0) {
          const size_t off = (size_t)(t & 1) * 32768 + (size_t)eb * 512 + ec;
          st8(h1pub + off, (unsigned long long)pack2(hc, hc1) |
                           ((unsigned long long)pack2(hc2, hc3) << 32));
        }
      }
    }
    // release: ONLY the publishes are outstanding here (out[] moved below flag)
    asm volatile("s_waitcnt vmcnt(0)" ::: "memory");
    __syncthreads();   // S3: all waves' publishes acked before the flag
    if (tid == 0)
      __hip_atomic_store(&flags[(size_t)s * 256 + wg], (unsigned short)(s + 1),
                         __ATOMIC_RELAXED, __HIP_MEMORY_SCOPE_AGENT);

    // ---- off-critical-path stores (plain, cached) ----
    if (act) {
      if (pipe == 1) {
        out[(size_t)eb * 262144 + (size_t)t * 512 + ec] = oprev;                      // output
        if (t == TT - 1) out[(size_t)(16777216 + 32768) + (size_t)eb * 512 + ec] = hcar;  // h1f
      } else if (s == TT - 1) {
        out[(size_t)16777216 + (size_t)eb * 512 + ec] = hcar;                         // h0f
      }
    }
  }
}

extern "C" void kernel_launch(void* const* d_in, const int* in_sizes, int n_in,
                              void* d_out, int out_size, void* d_ws, size_t ws_size,
                              hipStream_t stream) {
  (void)in_sizes; (void)n_in; (void)out_size;
  const float* x    = (const float*)d_in[0];
  const int*   mask = (const int*)  d_in[1];
  const float* W0   = (const float*)d_in[2];
  const float* U0   = (const float*)d_in[3];
  const float* b0   = (const float*)d_in[4];
  const float* W1   = (const float*)d_in[5];
  const float* U1   = (const float*)d_in[6];
  const float* b1   = (const float*)d_in[7];
  float* out = (float*)d_out;
  unsigned char* ws = (unsigned char*)d_ws;

  const size_t need = 655872;   // pub buffers + h0n + u16 flags
  const size_t zb = ws_size < need ? ws_size : need;
  hipMemsetAsync(d_ws, 0, zb, stream);

  hipFuncSetAttribute((const void*)gru2_lockstep,
                      hipFuncAttributeMaxDynamicSharedMemorySize, 120320);
  void* args[] = { (void*)&x, (void*)&mask, (void*)&W0, (void*)&U0, (void*)&b0,
                   (void*)&W1, (void*)&U1, (void*)&b1, (void*)&out, (void*)&ws };
  hipLaunchCooperativeKernel((void*)gru2_lockstep, dim3(256), dim3(256),
                             args, 120320, stream);
}

// Round 3
// 4123.169 us; speedup vs baseline: 1.0356x; 1.0356x over previous
//
#include <hip/hip_runtime.h>
#include <stdint.h>

// 2-layer masked GRU encoder, B=64 T=512 D=U=512. f32 in/out, mask=int32.
// 256 WGs lockstep, software-pipelined: even WGs (pipe A) = layer 0 at phase s,
// odd WGs (pipe B) = layer 1 at phase s-1. One flag-barrier per phase.
// All cross-WG data via RELAXED agent-scope atomics (sc1, MALL-coherent).
// r3 == r2 with the staging-chunk bug fixed (j*16 -> j*8):
//   * cooperative LDS staging (one coalesced MALL RTT per phase)
//   * 4 independent row-group barriers (64 WGs each; WG(mi,ni) only reads
//     rows of its own mi) -- 128B flag footprint, 4x less poll contention
//   * XOR-swizzled st0/st1 + lane-contiguous accs (bank-conflict-free)
//   * register shfl publish (no pub16 LDS, 4 syncs/phase)
//   * out[]/final-h stores after the flag => release vmcnt(0) waits only
//     on the tiny publishes
// ws: h0pub[2][64][512]bf16 | h1pub[2][64][512]bf16 | h0n[2][64][512]bf16
//     | flags[513][4][64]u16   == 655,872 bytes.

#define TT 512

typedef __attribute__((ext_vector_type(8))) short bfrag_t;   // 8 x bf16
typedef __attribute__((ext_vector_type(4))) float f32x4;

__device__ inline unsigned short f2bf(float f) {
  unsigned u = __float_as_uint(f);
  unsigned r = u + 0x7FFFu + ((u >> 16) & 1u);   // RNE
  return (unsigned short)(r >> 16);
}
__device__ inline unsigned pack2(float lo, float hi) {
  return (unsigned)f2bf(lo) | ((unsigned)f2bf(hi) << 16);
}
__device__ inline float sigmoidf_(float x) { return 1.0f / (1.0f + __expf(-x)); }
__device__ inline float fast_tanh(float x) {
  float ax = fabsf(x);
  float e = __expf(-2.0f * ax);
  float t = (1.0f - e) / (1.0f + e);
  return x < 0.0f ? -t : t;
}

__device__ inline void st8(void* p, unsigned long long v) {
  __hip_atomic_store((unsigned long long*)p, v, __ATOMIC_RELAXED, __HIP_MEMORY_SCOPE_AGENT);
}
__device__ inline unsigned long long ld8(const void* p) {
  return __hip_atomic_load((const unsigned long long*)p, __ATOMIC_RELAXED, __HIP_MEMORY_SCOPE_AGENT);
}

// Group barrier: 64 u16 flags (128B). Lanes replicate over 16 u64 words.
// One load per lane per poll.
__device__ inline void spingroup(const unsigned short* f, int s_expect) {
  const int lane = threadIdx.x & 63;
  const unsigned long long* p = (const unsigned long long*)f + (lane & 15);
  const unsigned long long rep = 0x0001000100010001ull * (unsigned long long)s_expect;
  for (;;) {
    unsigned long long v = __hip_atomic_load(p, __ATOMIC_RELAXED, __HIP_MEMORY_SCOPE_AGENT);
    if (__ballot(v == rep) == 0xFFFFFFFFFFFFFFFFull) break;
    __builtin_amdgcn_s_sleep(1);   // ~64cy backoff: keeps flag lines writable
  }
}

extern "C" __global__ void __launch_bounds__(256, 1)
gru2_lockstep(const float* __restrict__ x,     // [64][512][512] f32
              const int*   __restrict__ mask,  // [64][512] i32
              const float* __restrict__ W0,    // [512][1536] f32
              const float* __restrict__ U0,
              const float* __restrict__ b0,    // [2][1536]
              const float* __restrict__ W1,
              const float* __restrict__ U1,
              const float* __restrict__ b1,
              float* __restrict__ out,         // [16777216 + 2*32768] f32
              unsigned char* __restrict__ ws)
{
  extern __shared__ unsigned short sm[];
  unsigned short* wt  = sm;                 // [96][520] bf16 transposed weights
  unsigned short* st0 = sm + 96 * 520;      // [16][512] x / h0n operand, XOR-swizzled
  unsigned short* st1 = st0 + 16 * 512;     // [16][512] hidden operand, XOR-swizzled
  float* accs = (float*)(st1 + 16 * 512);   // [4][256] lane-contiguous

  unsigned short* h0pub = (unsigned short*)ws;             // [2][64][512] bf16 (masked h0)
  unsigned short* h1pub = (unsigned short*)(ws + 131072);  // [2][64][512] bf16 (masked h1)
  unsigned short* h0n   = (unsigned short*)(ws + 262144);  // [2][64][512] bf16 (UNMASKED h0n)
  unsigned short* flags = (unsigned short*)(ws + 393216);  // [513][4][64] u16

  const int tid  = threadIdx.x;
  const int wg   = blockIdx.x;
  const int pipe = wg & 1;
  const int idx  = wg >> 1;
  const int mi = idx & 3,  ni = idx >> 2;
  const int r0 = mi * 16,  c0 = ni * 16;
  const int member = (ni << 1) | pipe;      // 0..63 within row-group mi
  const int wave = tid >> 6, lane = tid & 63;
  const int quad = lane >> 4, n16 = lane & 15;

  const float* Wm = pipe ? W1 : W0;
  const float* Um = pipe ? U1 : U0;
  const float* bp = pipe ? b1 : b0;
  unsigned short* hpub = pipe ? h1pub : h0pub;

  // ---- one-time: transpose my 48 gate-cols of W and U into LDS bf16 [n][k] ----
  {
    const int col  = tid & 15;
    const int ksub = tid >> 4;
    for (int k0 = 0; k0 < 512; k0 += 16) {
      const int k = k0 + ksub;
      const float* M0 = Wm + (size_t)k * 1536;
      const float* M1 = Um + (size_t)k * 1536;
      #pragma unroll
      for (int g = 0; g < 3; ++g) {
        wt[(g * 16 + col) * 520 + k]      = f2bf(M0[g * 512 + c0 + col]);
        wt[(48 + g * 16 + col) * 520 + k] = f2bf(M1[g * 512 + c0 + col]);
      }
    }
  }
  __syncthreads();

  // wave roles: w0=z (concat x|h), w1=r (concat), w2=ih (x), w3=hh (h)
  const int g  = (wave < 2) ? wave : 2;
  const int np = (wave < 2) ? 2 : 1;

  bfrag_t bw0[16], bw1[16];
  {
    const int mat0 = (wave == 3) ? 1 : 0;
    const int row0 = mat0 * 48 + g * 16 + n16;
    #pragma unroll
    for (int f = 0; f < 16; ++f)
      bw0[f] = *(const bfrag_t*)&wt[row0 * 520 + f * 32 + quad * 8];
    if (np == 2) {
      const int row1 = 48 + g * 16 + n16;
      #pragma unroll
      for (int f = 0; f < 16; ++f)
        bw1[f] = *(const bfrag_t*)&wt[row1 * 520 + f * 32 + quad * 8];
    }
  }

  float bsc;
  {
    const int colg = g * 512 + c0 + n16;
    const float bi = bp[colg];
    const float bh = bp[1536 + colg];
    bsc = (wave < 2) ? (bi + bh) : ((wave == 2) ? bi : bh);
  }

  float hcar = 0.0f;   // fp32 carry of my h element (WG-local!)
  float oprev = 0.0f;
  const int erow = tid >> 4, ecol = tid & 15;
  const int eb = r0 + erow, ec = c0 + ecol;

  for (int s = 0; s <= TT; ++s) {
    const bool actA = (pipe == 0) && (s < TT);
    const bool actB = (pipe == 1) && (s > 0);
    const bool act  = actA || actB;
    const int  t    = pipe ? (s - 1) : s;

    // mask prefetch (regular cached load, overlapped with everything below)
    const int mv = act ? mask[(size_t)eb * 512 + t] : 0;

    // ---- barrier wait (wave 0) overlapped with pipe-A x(s) prestage ----
    if (actA && tid >= 128) {
      const int sm2 = (tid - 128) >> 3;     // 0..15 row
      const int k8  = tid & 7;              // 0..7 chunk sub-index
      const float* src = x + (((size_t)(r0 + sm2) * 512 + s) * 512 + k8 * 8);
      uint4* dstrow = (uint4*)(st0 + sm2 * 512);
      #pragma unroll
      for (int c = 0; c < 8; ++c) {
        float4 a = *(const float4*)(src + c * 64);
        float4 b = *(const float4*)(src + c * 64 + 4);
        uint4 u;
        u.x = pack2(a.x, a.y);  u.y = pack2(a.z, a.w);
        u.z = pack2(b.x, b.y);  u.w = pack2(b.z, b.w);
        dstrow[(k8 + 8 * c) ^ (sm2 & 7)] = u;   // XOR-swizzled chunk
      }
    } else if (wave == 0 && s > 0) {
      spingroup(flags + (size_t)(s - 1) * 256 + mi * 64, s);
    }
    __syncthreads();   // S1: group flags confirmed + st0(x) ready

    // ---- cooperative stage: st1 <- hpub (and pipe B: st0 <- h0n), swizzled ----
    if (act) {
      const int row = tid >> 4;             // 0..15
      const int cb  = (tid & 15) * 4;       // chunk base (chunks of 8 elems)
      const size_t goff = (size_t)(r0 + row) * 512 + (size_t)cb * 8;
      const unsigned short* hsrc = hpub + (size_t)((t + 1) & 1) * 32768 + goff;
      uint4* dst1 = (uint4*)(st1 + row * 512);
      const int swr = row & 7;
      #pragma unroll
      for (int j = 0; j < 4; ++j) {
        unsigned long long lo = ld8(hsrc + j * 8);
        unsigned long long hi = ld8(hsrc + j * 8 + 4);
        uint4 u;
        u.x = (unsigned)lo;  u.y = (unsigned)(lo >> 32);
        u.z = (unsigned)hi;  u.w = (unsigned)(hi >> 32);
        dst1[(cb + j) ^ swr] = u;
      }
      if (pipe == 1) {
        const unsigned short* nsrc = h0n + (size_t)(t & 1) * 32768 + goff;
        uint4* dst0 = (uint4*)(st0 + row * 512);
        #pragma unroll
        for (int j = 0; j < 4; ++j) {
          unsigned long long lo = ld8(nsrc + j * 8);
          unsigned long long hi = ld8(nsrc + j * 8 + 4);
          uint4 u;
          u.x = (unsigned)lo;  u.y = (unsigned)(lo >> 32);
          u.z = (unsigned)hi;  u.w = (unsigned)(hi >> 32);
          dst0[(cb + j) ^ swr] = u;
        }
      }
    }
    __syncthreads();   // S2: operands staged

    // ---- MFMA (LDS reads, swizzled, bank-balanced) ----
    if (act) {
      f32x4 acc = {bsc, bsc, bsc, bsc};
      const unsigned short* s0 = (wave == 3) ? st1 : st0;
      const int rbase = n16 * 512;
      const int sw = n16 & 7;
      #pragma unroll
      for (int f = 0; f < 16; ++f) {
        bfrag_t a = *(const bfrag_t*)&s0[rbase + (((4 * f + quad) ^ sw) << 3)];
        acc = __builtin_amdgcn_mfma_f32_16x16x32_bf16(a, bw0[f], acc, 0, 0, 0);
      }
      if (np == 2) {
        #pragma unroll
        for (int f = 0; f < 16; ++f) {
          bfrag_t a = *(const bfrag_t*)&st1[rbase + (((4 * f + quad) ^ sw) << 3)];
          acc = __builtin_amdgcn_mfma_f32_16x16x32_bf16(a, bw1[f], acc, 0, 0, 0);
        }
      }
      // lane-contiguous b128 store: conflict-free
      *(f32x4*)&accs[wave * 256 + lane * 4] = acc;
    }
    __syncthreads();   // S3: accs ready

    // ---- elementwise GRU cell + in-register publish pack ----
    if (act) {
      const int aidx = ((erow >> 2) * 16 + ecol) * 4 + (erow & 3);
      const float zv = sigmoidf_(accs[aidx]);
      const float rv = sigmoidf_(accs[256 + aidx]);
      const float candv = fast_tanh(accs[512 + aidx] + rv * accs[768 + aidx]);
      const float hold = hcar;
      const float hn = zv * hold + (1.0f - zv) * candv;
      const bool  m  = mv != 0;
      const float hc = m ? hn : hold;
      hcar = hc;
      if (pipe == 1) oprev = m ? hn : oprev;

      // pack 4 neighboring columns (lanes l..l+3, never crossing a 16-lane row)
      const float hc1 = __shfl_down(hc, 1);
      const float hc2 = __shfl_down(hc, 2);
      const float hc3 = __shfl_down(hc, 3);
      if (pipe == 0) {
        const float hn1 = __shfl_down(hn, 1);
        const float hn2 = __shfl_down(hn, 2);
        const float hn3 = __shfl_down(hn, 3);
        if ((tid & 3) == 0) {
          const size_t off = (size_t)(t & 1) * 32768 + (size_t)eb * 512 + ec;
          st8(h0pub + off, (unsigned long long)pack2(hc, hc1) |
                           ((unsigned long long)pack2(hc2, hc3) << 32));
          st8(h0n + off,   (unsigned long long)pack2(hn, hn1) |
                           ((unsigned long long)pack2(hn2, hn3) << 32));
        }
      } else {
        if ((tid & 3) == 0) {
          const size_t off = (size_t)(t & 1) * 32768 + (size_t)eb * 512 + ec;
          st8(h1pub + off, (unsigned long long)pack2(hc, hc1) |
                           ((unsigned long long)pack2(hc2, hc3) << 32));
        }
      }
    }
    // release: ONLY the publishes are outstanding here (out[] moved below flag)
    asm volatile("s_waitcnt vmcnt(0)" ::: "memory");
    __syncthreads();   // S4: all waves' publishes acked before the flag
    if (tid == 0)
      __hip_atomic_store(&flags[(size_t)s * 256 + mi * 64 + member],
                         (unsigned short)(s + 1),
                         __ATOMIC_RELAXED, __HIP_MEMORY_SCOPE_AGENT);

    // ---- off-critical-path stores (plain, cached) ----
    if (act) {
      if (pipe == 1) {
        out[(size_t)eb * 262144 + (size_t)t * 512 + ec] = oprev;                      // output
        if (t == TT - 1) out[(size_t)(16777216 + 32768) + (size_t)eb * 512 + ec] = hcar;  // h1f
      } else if (s == TT - 1) {
        out[(size_t)16777216 + (size_t)eb * 512 + ec] = hcar;                         // h0f
      }
    }
  }
}

extern "C" void kernel_launch(void* const* d_in, const int* in_sizes, int n_in,
                              void* d_out, int out_size, void* d_ws, size_t ws_size,
                              hipStream_t stream) {
  (void)in_sizes; (void)n_in; (void)out_size;
  const float* x    = (const float*)d_in[0];
  const int*   mask = (const int*)  d_in[1];
  const float* W0   = (const float*)d_in[2];
  const float* U0   = (const float*)d_in[3];
  const float* b0   = (const float*)d_in[4];
  const float* W1   = (const float*)d_in[5];
  const float* U1   = (const float*)d_in[6];
  const float* b1   = (const float*)d_in[7];
  float* out = (float*)d_out;
  unsigned char* ws = (unsigned char*)d_ws;

  const size_t need = 655872;   // pub buffers + h0n + u16 group flags
  const size_t zb = ws_size < need ? ws_size : need;
  hipMemsetAsync(d_ws, 0, zb, stream);

  hipFuncSetAttribute((const void*)gru2_lockstep,
                      hipFuncAttributeMaxDynamicSharedMemorySize, 136704);
  void* args[] = { (void*)&x, (void*)&mask, (void*)&W0, (void*)&U0, (void*)&b0,
                   (void*)&W1, (void*)&U1, (void*)&b1, (void*)&out, (void*)&ws };
  hipLaunchCooperativeKernel((void*)gru2_lockstep, dim3(256), dim3(256),
                             args, 136704, stream);
}

// Round 5
// 2454.030 us; speedup vs baseline: 1.7400x; 1.6802x over previous
//
#include <hip/hip_runtime.h>
#include <stdint.h>

// 2-layer masked GRU encoder, B=64 T=512 D=U=512. f32 in/out, mask=int32.
// 256 WGs lockstep, software-pipelined: even WGs (pipe A) = layer 0 at phase s,
// odd WGs (pipe B) = layer 1 at phase s-1. One flag-barrier per phase.
// All cross-WG data via RELAXED agent-scope atomics (sc1, MALL-coherent) --
// no acquire/release fences => no buffer_inv / buffer_wbl2 L2 tag sweeps.
// fp32 h-carry lives in registers (1 elem/thread); only bf16 h published.
// r5 == r4 resubmitted verbatim (round-4 bench was an infra failure:
// container acquisition failed; no kernel signal).
// r4 == r0 (2702us proven) + ONE delta: 4 independent row-group barriers.
//   WG(mi,ni) only consumes tiles produced by the 64 WGs sharing mi, so it
//   waits on 64 u32 flags (1 load/lane/poll, was 4) instead of 256.
// ws: h0pub[2][64][512]bf16 | h1pub[2][64][512]bf16 | h0n[2][64][512]bf16
//     | flags[513][4][64]u32   == 918,528 bytes.

#define TT 512

typedef __attribute__((ext_vector_type(8))) short bfrag_t;   // 8 x bf16
typedef __attribute__((ext_vector_type(4))) float f32x4;

__device__ inline unsigned short f2bf(float f) {
  unsigned u = __float_as_uint(f);
  unsigned r = u + 0x7FFFu + ((u >> 16) & 1u);   // RNE
  return (unsigned short)(r >> 16);
}
__device__ inline unsigned pack2(float lo, float hi) {
  return (unsigned)f2bf(lo) | ((unsigned)f2bf(hi) << 16);
}
__device__ inline float sigmoidf_(float x) { return 1.0f / (1.0f + __expf(-x)); }
__device__ inline float fast_tanh(float x) {
  float ax = fabsf(x);
  float e = __expf(-2.0f * ax);
  float t = (1.0f - e) / (1.0f + e);
  return x < 0.0f ? -t : t;
}

__device__ inline void st8(void* p, unsigned long long v) {
  __hip_atomic_store((unsigned long long*)p, v, __ATOMIC_RELAXED, __HIP_MEMORY_SCOPE_AGENT);
}
__device__ inline unsigned long long ld8(const void* p) {
  return __hip_atomic_load((const unsigned long long*)p, __ATOMIC_RELAXED, __HIP_MEMORY_SCOPE_AGENT);
}

// Row-group barrier: wait until all 64 group flags == expect.
// ONE relaxed u32 load per lane per poll (no sleep).
__device__ inline void spingroup(const unsigned* f, unsigned expect) {
  const unsigned* p = f + (threadIdx.x & 63);
  for (;;) {
    unsigned v = __hip_atomic_load(p, __ATOMIC_RELAXED, __HIP_MEMORY_SCOPE_AGENT);
    if (__ballot(v == expect) == 0xFFFFFFFFFFFFFFFFull) break;
  }
}

extern "C" __global__ void __launch_bounds__(256, 1)
gru2_lockstep(const float* __restrict__ x,     // [64][512][512] f32
              const int*   __restrict__ mask,  // [64][512] i32
              const float* __restrict__ W0,    // [512][1536] f32
              const float* __restrict__ U0,
              const float* __restrict__ b0,    // [2][1536]
              const float* __restrict__ W1,
              const float* __restrict__ U1,
              const float* __restrict__ b1,
              float* __restrict__ out,         // [16777216 + 2*32768] f32
              unsigned char* __restrict__ ws)
{
  extern __shared__ unsigned short sm[];
  unsigned short* wt  = sm;                 // [96][520] bf16 transposed weights
  unsigned short* st0 = sm + 96 * 520;      // [16][520] input operand (x or h0n)
  unsigned short* st1 = st0 + 16 * 520;     // [16][520] hidden operand
  float* accs = (float*)(st1 + 16 * 520);   // [4][256]
  unsigned short* pub16 = (unsigned short*)(accs + 1024);  // [2][16][16] publish staging

  unsigned short* h0pub = (unsigned short*)ws;             // [2][64][512] bf16 (masked h0)
  unsigned short* h1pub = (unsigned short*)(ws + 131072);  // [2][64][512] bf16 (masked h1)
  unsigned short* h0n   = (unsigned short*)(ws + 262144);  // [2][64][512] bf16 (UNMASKED h0n)
  unsigned*       flags = (unsigned*)      (ws + 393216);  // [513][4][64] u32

  const int tid  = threadIdx.x;
  const int wg   = blockIdx.x;
  const int pipe = wg & 1;
  const int idx  = wg >> 1;
  const int mi = idx & 3,  ni = idx >> 2;
  const int r0 = mi * 16,  c0 = ni * 16;
  const int member = (ni << 1) | pipe;      // 0..63 within row-group mi
  const int wave = tid >> 6, lane = tid & 63;
  const int quad = lane >> 4, n16 = lane & 15;

  const float* Wm = pipe ? W1 : W0;
  const float* Um = pipe ? U1 : U0;
  const float* bp = pipe ? b1 : b0;
  unsigned short* hpub = pipe ? h1pub : h0pub;

  // ---- one-time: transpose my 48 gate-cols of W and U into LDS bf16 [n][k] ----
  {
    const int col  = tid & 15;
    const int ksub = tid >> 4;
    for (int k0 = 0; k0 < 512; k0 += 16) {
      const int k = k0 + ksub;
      const float* M0 = Wm + (size_t)k * 1536;
      const float* M1 = Um + (size_t)k * 1536;
      #pragma unroll
      for (int g = 0; g < 3; ++g) {
        wt[(g * 16 + col) * 520 + k]      = f2bf(M0[g * 512 + c0 + col]);
        wt[(48 + g * 16 + col) * 520 + k] = f2bf(M1[g * 512 + c0 + col]);
      }
    }
  }
  __syncthreads();

  // wave roles: w0=z (concat x|h), w1=r (concat), w2=ih (x), w3=hh (h)
  const int g  = (wave < 2) ? wave : 2;
  const int np = (wave < 2) ? 2 : 1;

  bfrag_t bw0[16], bw1[16];
  {
    const int mat0 = (wave == 3) ? 1 : 0;
    const int row0 = mat0 * 48 + g * 16 + n16;
    #pragma unroll
    for (int f = 0; f < 16; ++f)
      bw0[f] = *(const bfrag_t*)&wt[row0 * 520 + f * 32 + quad * 8];
    if (np == 2) {
      const int row1 = 48 + g * 16 + n16;
      #pragma unroll
      for (int f = 0; f < 16; ++f)
        bw1[f] = *(const bfrag_t*)&wt[row1 * 520 + f * 32 + quad * 8];
    }
  }

  float bsc;
  {
    const int colg = g * 512 + c0 + n16;
    const float bi = bp[colg];
    const float bh = bp[1536 + colg];
    bsc = (wave < 2) ? (bi + bh) : ((wave == 2) ? bi : bh);
  }

  float hcar = 0.0f;   // fp32 carry of my h element (WG-local!)
  float oprev = 0.0f;
  const int erow = tid >> 4, ecol = tid & 15;
  const int eb = r0 + erow, ec = c0 + ecol;

  for (int s = 0; s <= TT; ++s) {
    const bool actA = (pipe == 0) && (s < TT);
    const bool actB = (pipe == 1) && (s > 0);
    const bool act  = actA || actB;
    const int  t    = pipe ? (s - 1) : s;

    // mask prefetch (regular cached load, overlapped with everything below)
    const int mv = act ? mask[(size_t)eb * 512 + t] : 0;

    // ---- barrier wait (wave 0) overlapped with pipe-A x(s) prestage ----
    if (actA && tid >= 128) {
      const int sm2 = (tid - 128) >> 3;     // 0..15 row
      const int sk2 = (tid & 7) * 64;       // col start
      const float* src = x + (((size_t)(r0 + sm2) * 512 + s) * 512 + sk2);
      uint4* dst = (uint4*)(st0 + sm2 * 520 + sk2);
      #pragma unroll
      for (int c = 0; c < 8; ++c) {
        float4 a = ((const float4*)src)[2 * c];
        float4 b = ((const float4*)src)[2 * c + 1];
        uint4 u;
        u.x = pack2(a.x, a.y);  u.y = pack2(a.z, a.w);
        u.z = pack2(b.x, b.y);  u.w = pack2(b.z, b.w);
        dst[c] = u;
      }
    } else if (wave == 0 && s > 0) {
      spingroup(flags + (size_t)(s - 1) * 256 + mi * 64, (unsigned)s);
    }
    __syncthreads();

    // ---- stage hidden operand st1 <- hpub (bf16, sc1); pipe B: st0 <- h0n ----
    if (act) {
      const int row = tid >> 4;             // 0..15
      const int cofs = (tid & 15) * 32;     // bf16 elems
      const unsigned short* hsrc = hpub + (size_t)((t + 1) & 1) * 32768 +
                                   (size_t)(r0 + row) * 512 + cofs;
      #pragma unroll
      for (int j = 0; j < 8; ++j) {
        unsigned long long v = ld8(hsrc + j * 4);
        *(unsigned long long*)&st1[row * 520 + cofs + j * 4] = v;
      }
      if (pipe == 1) {
        const unsigned short* nsrc = h0n + (size_t)(t & 1) * 32768 +
                                     (size_t)(r0 + row) * 512 + cofs;
        #pragma unroll
        for (int j = 0; j < 8; ++j) {
          unsigned long long v = ld8(nsrc + j * 4);
          *(unsigned long long*)&st0[row * 520 + cofs + j * 4] = v;
        }
      }
    }
    __syncthreads();

    // ---- MFMA ----
    if (act) {
      f32x4 acc = {bsc, bsc, bsc, bsc};
      const unsigned short* s0 = (wave == 3) ? st1 : st0;
      const int abase = n16 * 520 + quad * 8;
      #pragma unroll
      for (int f = 0; f < 16; ++f) {
        bfrag_t a = *(const bfrag_t*)&s0[abase + f * 32];
        acc = __builtin_amdgcn_mfma_f32_16x16x32_bf16(a, bw0[f], acc, 0, 0, 0);
      }
      if (np == 2) {
        #pragma unroll
        for (int f = 0; f < 16; ++f) {
          bfrag_t a = *(const bfrag_t*)&st1[abase + f * 32];
          acc = __builtin_amdgcn_mfma_f32_16x16x32_bf16(a, bw1[f], acc, 0, 0, 0);
        }
      }
      #pragma unroll
      for (int i = 0; i < 4; ++i)
        accs[wave * 256 + (quad * 4 + i) * 16 + n16] = acc[i];  // row=quad*4+i, col=n16
    }
    __syncthreads();

    // ---- elementwise GRU cell (register h-carry) ----
    if (act) {
      const float zv = sigmoidf_(accs[tid]);
      const float rv = sigmoidf_(accs[256 + tid]);
      const float candv = fast_tanh(accs[512 + tid] + rv * accs[768 + tid]);
      const float hold = hcar;
      const float hn = zv * hold + (1.0f - zv) * candv;
      const bool  m  = mv != 0;
      const float hc = m ? hn : hold;
      hcar = hc;
      pub16[erow * 16 + ecol] = f2bf(hc);
      if (pipe == 0) {
        pub16[256 + erow * 16 + ecol] = f2bf(hn);   // UNMASKED h0n for layer 1
        if (t == TT - 1) out[(size_t)16777216 + (size_t)eb * 512 + ec] = hc;         // h0f
      } else {
        const float ov = m ? hn : oprev;
        oprev = ov;
        out[(size_t)eb * 262144 + (size_t)t * 512 + ec] = ov;                         // output
        if (t == TT - 1) out[(size_t)16777216 + 32768 + (size_t)eb * 512 + ec] = hc;  // h1f
      }
    }
    __syncthreads();

    // ---- publish bf16 tiles (sc1 relaxed 8B stores) ----
    if (act) {
      const int nst = (pipe == 0) ? 128 : 64;
      if (tid < nst) {
        const int v  = tid >> 6;          // 0: masked h, 1: unmasked h0n (pipe A only)
        const int r  = (tid >> 2) & 15;
        const int sg = tid & 3;
        unsigned long long val = *(unsigned long long*)&pub16[v * 256 + r * 16 + sg * 4];
        unsigned short* dst;
        if (pipe == 0) dst = (v ? h0n : h0pub) + (size_t)(t & 1) * 32768;
        else           dst = h1pub + (size_t)(t & 1) * 32768;
        st8(dst + (size_t)(r0 + r) * 512 + c0 + sg * 4, val);
      }
    }
    asm volatile("s_waitcnt vmcnt(0)" ::: "memory");  // publishes complete (MALL)
    __syncthreads();
    if (tid == 0)
      __hip_atomic_store(&flags[(size_t)s * 256 + mi * 64 + member],
                         (unsigned)(s + 1),
                         __ATOMIC_RELAXED, __HIP_MEMORY_SCOPE_AGENT);
  }
}

extern "C" void kernel_launch(void* const* d_in, const int* in_sizes, int n_in,
                              void* d_out, int out_size, void* d_ws, size_t ws_size,
                              hipStream_t stream) {
  (void)in_sizes; (void)n_in; (void)out_size;
  const float* x    = (const float*)d_in[0];
  const int*   mask = (const int*)  d_in[1];
  const float* W0   = (const float*)d_in[2];
  const float* U0   = (const float*)d_in[3];
  const float* b0   = (const float*)d_in[4];
  const float* W1   = (const float*)d_in[5];
  const float* U1   = (const float*)d_in[6];
  const float* b1   = (const float*)d_in[7];
  float* out = (float*)d_out;
  unsigned char* ws = (unsigned char*)d_ws;

  const size_t need = 918528;   // pub buffers + h0n + u32 group flags
  const size_t zb = ws_size < need ? ws_size : need;
  hipMemsetAsync(d_ws, 0, zb, stream);

  hipFuncSetAttribute((const void*)gru2_lockstep,
                      hipFuncAttributeMaxDynamicSharedMemorySize, 139264);
  void* args[] = { (void*)&x, (void*)&mask, (void*)&W0, (void*)&U0, (void*)&b0,
                   (void*)&W1, (void*)&U1, (void*)&b1, (void*)&out, (void*)&ws };
  hipLaunchCooperativeKernel((void*)gru2_lockstep, dim3(256), dim3(256),
                             args, 139264, stream);
}

// Round 8
// 2117.499 us; speedup vs baseline: 2.0166x; 1.1589x over previous
//
#include <hip/hip_runtime.h>
#include <stdint.h>

// 2-layer masked GRU encoder, B=64 T=512 D=U=512. f32 in/out, mask=int32.
// 256 WGs lockstep: even WGs (pipe A) = layer 0 at phase s (t=s), odd WGs
// (pipe B) = layer 1 at phase s-2 (2-phase pipeline lag).
// r8 = r6 DE-RISKED after two Trio-level bench failures on r6:
//   * ALL flags are sc1 relaxed agent atomics (r5-proven machinery) -- the
//     liveness-critical spin path has NO sc0 anywhere. A data load/store
//     cannot hang; only spins can, and every spin edge is r5-proven.
//   * sc0 (XCD-L2-local) is used ONLY for bulk h0pub/h1pub publish+stage,
//     guarded by the runtime XCC_ID handshake (loc=false -> sc1 fallback,
//     == r5 semantics). Producer/consumer sc-mode is subgroup-consistent.
//   * B's 2-phase lag + quad-buffered h0n keep every cross-pipe sc1 edge
//     >=1 phase stale => off the critical path.
//   * single flag array, ONE post per phase (was two in r6).
// ws: h0pub[2][64][512]bf16 | h1pub[2][64][512]bf16 | h0n[4][64][512]bf16
//     | xcc[256]u32 | flags[4][4][2][32]u32  == 529,408 bytes.

#define TT 512

typedef __attribute__((ext_vector_type(8))) short bfrag_t;   // 8 x bf16
typedef __attribute__((ext_vector_type(4))) float f32x4;
typedef __attribute__((ext_vector_type(4))) unsigned uint4v;

__device__ inline unsigned short f2bf(float f) {
  unsigned u = __float_as_uint(f);
  unsigned r = u + 0x7FFFu + ((u >> 16) & 1u);   // RNE
  return (unsigned short)(r >> 16);
}
__device__ inline unsigned pack2(float lo, float hi) {
  return (unsigned)f2bf(lo) | ((unsigned)f2bf(hi) << 16);
}
__device__ inline float sigmoidf_(float x) { return 1.0f / (1.0f + __expf(-x)); }
__device__ inline float fast_tanh(float x) {
  float ax = fabsf(x);
  float e = __expf(-2.0f * ax);
  float t = (1.0f - e) / (1.0f + e);
  return x < 0.0f ? -t : t;
}

// ---- sc1 (MALL, agent-coherent) primitives ----
__device__ inline void st8(void* p, unsigned long long v) {
  __hip_atomic_store((unsigned long long*)p, v, __ATOMIC_RELAXED, __HIP_MEMORY_SCOPE_AGENT);
}
__device__ inline unsigned long long ld8(const void* p) {
  return __hip_atomic_load((const unsigned long long*)p, __ATOMIC_RELAXED, __HIP_MEMORY_SCOPE_AGENT);
}
// ---- dual-mode DATA primitives: sc0 (XCD-L2-local) when l2, else sc1 ----
__device__ inline void st8c(void* p, unsigned long long v, bool l2) {
  if (l2) asm volatile("global_store_dwordx2 %0, %1, off sc0" :: "v"(p), "v"(v) : "memory");
  else st8(p, v);
}
// 64B batched load (4 x dwordx4), one waitcnt.
__device__ inline void ld64c(const void* p, uint4v& a, uint4v& b, uint4v& c, uint4v& d, bool l2) {
  if (l2) {
    asm volatile(
      "global_load_dwordx4 %0, %4, off sc0\n\t"
      "global_load_dwordx4 %1, %4, off offset:16 sc0\n\t"
      "global_load_dwordx4 %2, %4, off offset:32 sc0\n\t"
      "global_load_dwordx4 %3, %4, off offset:48 sc0\n\t"
      "s_waitcnt vmcnt(0)"
      : "=&v"(a), "=&v"(b), "=&v"(c), "=&v"(d) : "v"(p) : "memory");
  } else {
    const unsigned long long* q = (const unsigned long long*)p;
    unsigned long long v0 = ld8(q+0), v1 = ld8(q+1), v2 = ld8(q+2), v3 = ld8(q+3);
    unsigned long long v4 = ld8(q+4), v5 = ld8(q+5), v6 = ld8(q+6), v7 = ld8(q+7);
    a = uint4v{(unsigned)v0, (unsigned)(v0>>32), (unsigned)v1, (unsigned)(v1>>32)};
    b = uint4v{(unsigned)v2, (unsigned)(v2>>32), (unsigned)v3, (unsigned)(v3>>32)};
    c = uint4v{(unsigned)v4, (unsigned)(v4>>32), (unsigned)v5, (unsigned)(v5>>32)};
    d = uint4v{(unsigned)v6, (unsigned)(v6>>32), (unsigned)v7, (unsigned)(v7>>32)};
  }
}

// 32-flag spin, value-based (>=), sc1 relaxed ONLY (r5-proven machinery).
__device__ inline void spin32(const unsigned* f, unsigned expect) {
  const int lane = threadIdx.x & 63;
  const unsigned* p = f + (lane & 31);
  for (;;) {
    unsigned v = __hip_atomic_load(p, __ATOMIC_RELAXED, __HIP_MEMORY_SCOPE_AGENT);
    if (__ballot((v >= expect) || (lane >= 32)) == 0xFFFFFFFFFFFFFFFFull) break;
  }
}

extern "C" __global__ void __launch_bounds__(256, 1)
gru2_lockstep(const float* __restrict__ x,     // [64][512][512] f32
              const int*   __restrict__ mask,  // [64][512] i32
              const float* __restrict__ W0,    // [512][1536] f32
              const float* __restrict__ U0,
              const float* __restrict__ b0,    // [2][1536]
              const float* __restrict__ W1,
              const float* __restrict__ U1,
              const float* __restrict__ b1,
              float* __restrict__ out,         // [16777216 + 2*32768] f32
              unsigned char* __restrict__ ws)
{
  extern __shared__ unsigned short sm[];
  unsigned short* wt  = sm;                 // [96][520] bf16 transposed weights
  unsigned short* st0 = sm + 96 * 520;      // [16][520] input operand (x or h0n)
  unsigned short* st1 = st0 + 16 * 520;     // [16][520] hidden operand
  float* accs = (float*)(st1 + 16 * 520);   // [4][256]
  unsigned short* pub16 = (unsigned short*)(accs + 1024);  // [2][16][16] publish staging

  unsigned short* h0pub = (unsigned short*)ws;             // [2][64][512] (masked h0, XCD-local)
  unsigned short* h1pub = (unsigned short*)(ws + 131072);  // [2][64][512] (masked h1, XCD-local)
  unsigned short* h0n   = (unsigned short*)(ws + 262144);  // [4][64][512] (UNMASKED h0n, sc1)
  unsigned*       xcc   = (unsigned*)      (ws + 524288);  // [256]
  unsigned*       flags = (unsigned*)      (ws + 525312);  // [4][4][2][32] u32, sc1

  const int tid  = threadIdx.x;
  const int wg   = blockIdx.x;
  const int pipe = wg & 1;
  const int idx  = wg >> 1;
  const int mi = idx & 3,  ni = idx >> 2;
  const int r0 = mi * 16,  c0 = ni * 16;
  const int wave = tid >> 6, lane = tid & 63;
  const int quad = lane >> 4, n16 = lane & 15;

  const float* Wm = pipe ? W1 : W0;
  const float* Um = pipe ? U1 : U0;
  const float* bp = pipe ? b1 : b0;
  unsigned short* hpub = pipe ? h1pub : h0pub;

  // ---- publish my XCC id immediately (handshake overlaps weight transpose) ----
  unsigned myx;
  asm volatile("s_getreg_b32 %0, hwreg(HW_REG_XCC_ID)" : "=s"(myx));
  if (tid == 0)
    __hip_atomic_store(&xcc[wg], myx + 1, __ATOMIC_RELAXED, __HIP_MEMORY_SCOPE_AGENT);

  // ---- one-time: transpose my 48 gate-cols of W and U into LDS bf16 [n][k] ----
  {
    const int col  = tid & 15;
    const int ksub = tid >> 4;
    for (int k0 = 0; k0 < 512; k0 += 16) {
      const int k = k0 + ksub;
      const float* M0 = Wm + (size_t)k * 1536;
      const float* M1 = Um + (size_t)k * 1536;
      #pragma unroll
      for (int g = 0; g < 3; ++g) {
        wt[(g * 16 + col) * 520 + k]      = f2bf(M0[g * 512 + c0 + col]);
        wt[(48 + g * 16 + col) * 520 + k] = f2bf(M1[g * 512 + c0 + col]);
      }
    }
  }

  // ---- finish handshake: all posted, then subgroup locality check (sc1) ----
  bool loc;
  {
    const unsigned* px = xcc + 4 * lane;
    for (;;) {
      unsigned a = __hip_atomic_load(px+0, __ATOMIC_RELAXED, __HIP_MEMORY_SCOPE_AGENT);
      unsigned b = __hip_atomic_load(px+1, __ATOMIC_RELAXED, __HIP_MEMORY_SCOPE_AGENT);
      unsigned c = __hip_atomic_load(px+2, __ATOMIC_RELAXED, __HIP_MEMORY_SCOPE_AGENT);
      unsigned d = __hip_atomic_load(px+3, __ATOMIC_RELAXED, __HIP_MEMORY_SCOPE_AGENT);
      if (__ballot(a && b && c && d) == 0xFFFFFFFFFFFFFFFFull) break;
    }
    unsigned ref = myx + 1, peerv = ref;
    if (lane < 32)
      peerv = __hip_atomic_load(&xcc[pipe + 2*mi + 8*(lane & 31)],
                                __ATOMIC_RELAXED, __HIP_MEMORY_SCOPE_AGENT);
    loc = (__ballot(peerv == ref) == 0xFFFFFFFFFFFFFFFFull);
  }
  __syncthreads();

  // wave roles: w0=z (concat x|h), w1=r (concat), w2=ih (x), w3=hh (h)
  const int g  = (wave < 2) ? wave : 2;
  const int np = (wave < 2) ? 2 : 1;

  bfrag_t bw0[16], bw1[16];
  {
    const int mat0 = (wave == 3) ? 1 : 0;
    const int row0 = mat0 * 48 + g * 16 + n16;
    #pragma unroll
    for (int f = 0; f < 16; ++f)
      bw0[f] = *(const bfrag_t*)&wt[row0 * 520 + f * 32 + quad * 8];
    if (np == 2) {
      const int row1 = 48 + g * 16 + n16;
      #pragma unroll
      for (int f = 0; f < 16; ++f)
        bw1[f] = *(const bfrag_t*)&wt[row1 * 520 + f * 32 + quad * 8];
    }
  }

  float bsc;
  {
    const int colg = g * 512 + c0 + n16;
    const float bi = bp[colg];
    const float bh = bp[1536 + colg];
    bsc = (wave < 2) ? (bi + bh) : ((wave == 2) ? bi : bh);
  }

  float hcar = 0.0f;   // fp32 carry of my h element (WG-local!)
  float oprev = 0.0f;
  const int erow = tid >> 4, ecol = tid & 15;
  const int eb = r0 + erow, ec = c0 + ecol;

  for (int s = 0; s <= TT + 1; ++s) {
    const bool actA = (pipe == 0) && (s < TT);
    const bool actB = (pipe == 1) && (s >= 2);
    const bool act  = actA || actB;
    const int  t    = pipe ? (s - 2) : s;

    // mask prefetch (regular cached load, overlapped with everything below)
    const int mv = act ? mask[(size_t)eb * 512 + t] : 0;

    // ---- phase-start spins (waves 0,1) overlapped with pipe-A x(s) prestage ----
    if ((pipe == 0) && (s < TT) && tid >= 128) {
      const int sm2 = (tid - 128) >> 3;     // 0..15 row
      const int sk2 = (tid & 7) * 64;       // col start
      const float* src = x + (((size_t)(r0 + sm2) * 512 + s) * 512 + sk2);
      uint4* dst = (uint4*)(st0 + sm2 * 520 + sk2);
      #pragma unroll
      for (int c = 0; c < 8; ++c) {
        float4 a = ((const float4*)src)[2 * c];
        float4 b = ((const float4*)src)[2 * c + 1];
        uint4 u;
        u.x = pack2(a.x, a.y);  u.y = pack2(a.z, a.w);
        u.z = pack2(b.x, b.y);  u.w = pack2(b.z, b.w);
        dst[c] = u;
      }
    }
    if (wave == 0 && s > 0) {
      // own-pipe peers finished phase s-1 (data readiness + local overwrite safety)
      spin32(flags + ((((s - 1) & 3) * 4 + mi) * 2 + pipe) * 32, (unsigned)s);
    } else if (wave == 1 && s >= 2) {
      // other pipe finished phase s-2 (>=1-phase-stale cross checks):
      // A: B's reads of the h0n slot I overwrite this phase are done.
      // B: A published the h0n slot I stage this phase.
      spin32(flags + ((((s - 2) & 3) * 4 + mi) * 2 + (1 - pipe)) * 32, (unsigned)(s - 1));
    }
    __syncthreads();

    // ---- stage hidden operand st1 <- hpub (sc0 if loc); pipe B: st0 <- h0n (sc1) ----
    if (act) {
      const int row = tid >> 4;             // 0..15
      const int cofs = (tid & 15) * 32;     // bf16 elems
      const size_t goff = (size_t)(r0 + row) * 512 + cofs;
      unsigned long long n0=0,n1=0,n2=0,n3=0,n4=0,n5=0,n6=0,n7=0;
      if (pipe == 1) {   // issue MALL loads first so they overlap the local ones
        const unsigned short* nsrc = h0n + (size_t)(t & 3) * 32768 + goff;
        n0 = ld8(nsrc + 0);  n1 = ld8(nsrc + 4);  n2 = ld8(nsrc + 8);  n3 = ld8(nsrc + 12);
        n4 = ld8(nsrc + 16); n5 = ld8(nsrc + 20); n6 = ld8(nsrc + 24); n7 = ld8(nsrc + 28);
      }
      uint4v a, b, c, d;
      ld64c(hpub + (size_t)((t + 1) & 1) * 32768 + goff, a, b, c, d, loc);
      uint4v* d1 = (uint4v*)&st1[row * 520 + cofs];
      d1[0] = a; d1[1] = b; d1[2] = c; d1[3] = d;
      if (pipe == 1) {
        unsigned long long* d0 = (unsigned long long*)&st0[row * 520 + cofs];
        d0[0] = n0; d0[1] = n1; d0[2] = n2; d0[3] = n3;
        d0[4] = n4; d0[5] = n5; d0[6] = n6; d0[7] = n7;
      }
    }
    __syncthreads();

    // ---- MFMA ----
    if (act) {
      f32x4 acc = {bsc, bsc, bsc, bsc};
      const unsigned short* s0 = (wave == 3) ? st1 : st0;
      const int abase = n16 * 520 + quad * 8;
      #pragma unroll
      for (int f = 0; f < 16; ++f) {
        bfrag_t a = *(const bfrag_t*)&s0[abase + f * 32];
        acc = __builtin_amdgcn_mfma_f32_16x16x32_bf16(a, bw0[f], acc, 0, 0, 0);
      }
      if (np == 2) {
        #pragma unroll
        for (int f = 0; f < 16; ++f) {
          bfrag_t a = *(const bfrag_t*)&st1[abase + f * 32];
          acc = __builtin_amdgcn_mfma_f32_16x16x32_bf16(a, bw1[f], acc, 0, 0, 0);
        }
      }
      #pragma unroll
      for (int i = 0; i < 4; ++i)
        accs[wave * 256 + (quad * 4 + i) * 16 + n16] = acc[i];  // row=quad*4+i, col=n16
    }
    __syncthreads();

    // ---- elementwise GRU cell (register h-carry) ----
    if (act) {
      const float zv = sigmoidf_(accs[tid]);
      const float rv = sigmoidf_(accs[256 + tid]);
      const float candv = fast_tanh(accs[512 + tid] + rv * accs[768 + tid]);
      const float hold = hcar;
      const float hn = zv * hold + (1.0f - zv) * candv;
      const bool  m  = mv != 0;
      const float hc = m ? hn : hold;
      hcar = hc;
      pub16[erow * 16 + ecol] = f2bf(hc);
      if (pipe == 0) {
        pub16[256 + erow * 16 + ecol] = f2bf(hn);   // UNMASKED h0n for layer 1
      } else {
        oprev = m ? hn : oprev;
      }
    }
    __syncthreads();

    // ---- publish bf16 tiles ----
    if (act) {
      const int nst = (pipe == 0) ? 128 : 64;
      if (tid < nst) {
        const int v  = tid >> 6;          // 0: masked h, 1: unmasked h0n (pipe A only)
        const int r  = (tid >> 2) & 15;
        const int sg = tid & 3;
        unsigned long long val = *(unsigned long long*)&pub16[v * 256 + r * 16 + sg * 4];
        const size_t off = (size_t)(r0 + r) * 512 + c0 + sg * 4;
        if (pipe == 0) {
          if (v == 0) st8c(h0pub + (size_t)(t & 1) * 32768 + off, val, loc);     // XCD-local
          else        st8 (h0n   + (size_t)(t & 3) * 32768 + off, val);          // sc1 -> B
        } else {
          st8c(h1pub + (size_t)(t & 1) * 32768 + off, val, loc);                 // XCD-local
        }
      }
    }
    asm volatile("s_waitcnt vmcnt(0)" ::: "memory");  // publishes complete
    __syncthreads();
    if (tid == 0)
      __hip_atomic_store(flags + (((s & 3) * 4 + mi) * 2 + pipe) * 32 + ni,
                         (unsigned)(s + 1),
                         __ATOMIC_RELAXED, __HIP_MEMORY_SCOPE_AGENT);

    // ---- off-critical-path stores (plain, cached) ----
    if (act) {
      if (pipe == 1) {
        out[(size_t)eb * 262144 + (size_t)t * 512 + ec] = oprev;                      // output
        if (t == TT - 1) out[(size_t)(16777216 + 32768) + (size_t)eb * 512 + ec] = hcar;  // h1f
      } else if (t == TT - 1) {
        out[(size_t)16777216 + (size_t)eb * 512 + ec] = hcar;                         // h0f
      }
    }
  }
}

extern "C" void kernel_launch(void* const* d_in, const int* in_sizes, int n_in,
                              void* d_out, int out_size, void* d_ws, size_t ws_size,
                              hipStream_t stream) {
  (void)in_sizes; (void)n_in; (void)out_size;
  const float* x    = (const float*)d_in[0];
  const int*   mask = (const int*)  d_in[1];
  const float* W0   = (const float*)d_in[2];
  const float* U0   = (const float*)d_in[3];
  const float* b0   = (const float*)d_in[4];
  const float* W1   = (const float*)d_in[5];
  const float* U1   = (const float*)d_in[6];
  const float* b1   = (const float*)d_in[7];
  float* out = (float*)d_out;
  unsigned char* ws = (unsigned char*)d_ws;

  const size_t need = 529408;   // pub buffers + h0n(x4) + xcc + flags
  const size_t zb = ws_size < need ? ws_size : need;
  hipMemsetAsync(d_ws, 0, zb, stream);

  hipFuncSetAttribute((const void*)gru2_lockstep,
                      hipFuncAttributeMaxDynamicSharedMemorySize, 139264);
  void* args[] = { (void*)&x, (void*)&mask, (void*)&W0, (void*)&U0, (void*)&b0,
                   (void*)&W1, (void*)&U1, (void*)&b1, (void*)&out, (void*)&ws };
  hipLaunchCooperativeKernel((void*)gru2_lockstep, dim3(256), dim3(256),
                             args, 139264, stream);
}